// Round 6
// baseline (3530.448 us; speedup 1.0000x reference)
//
#include <hip/hip_runtime.h>
#include <stdint.h>
#include <math.h>

// Problem constants (from reference):
#define BB 8
#define CC 32
#define TT 3136      // 56*56
#define KK 9
#define OC 64

#define NEGINF (-3.0e38f)
#define BR 32        // rows per block
#define RT 8         // rows per thread (per scanner)
#define MT 2         // col accumulators per thread
#define BC 128       // cols per LDS tile
#define NTILE 25     // 24 full tiles + one 64-col tile
#define CAP 56       // candidate cap per row
#define EPS 1e-4f    // >= 2x fp32-vs-fp64 dot error (~1e-6); validated R5

__device__ __forceinline__ uint32_t f2s(float v) {
    uint32_t u = __float_as_uint(v);
    return (u & 0x80000000u) ? ~u : (u | 0x80000000u);
}
__device__ __forceinline__ float s2f(uint32_t u) {
    u = (u & 0x80000000u) ? (u & 0x7FFFFFFFu) : ~u;
    return __uint_as_float(u);
}

// ---------------------------------------------------------------------------
// Kernel 1: transposed copies + norms.
// ---------------------------------------------------------------------------
__global__ __launch_bounds__(256) void norm_kernel(
    const float* __restrict__ x, float* __restrict__ xnT,
    float* __restrict__ xfT, double* __restrict__ invn)
{
    int t = blockIdx.x * 256 + threadIdx.x;
    int b = blockIdx.y;
    if (t >= TT) return;
    const float* xp = x + (size_t)b * CC * TT + t;
    float v[CC];
    double ss = 0.0;
#pragma unroll
    for (int c = 0; c < CC; ++c) {
        v[c] = xp[(size_t)c * TT];
        ss = fma((double)v[c], (double)v[c], ss);
    }
    double inv = 1.0 / fmax(sqrt(ss), 1e-12);
    invn[(size_t)b * TT + t] = inv;
    float invf = (float)inv;
    float* pf = xfT + ((size_t)b * TT + t) * CC;
    float* pn = xnT + ((size_t)b * TT + t) * CC;
#pragma unroll
    for (int c = 0; c < CC; c += 4) {
        *(float4*)(pf + c) = make_float4(v[c], v[c+1], v[c+2], v[c+3]);
        *(float4*)(pn + c) = make_float4(v[c]*invf, v[c+1]*invf, v[c+2]*invf, v[c+3]*invf);
    }
}

// ---------------------------------------------------------------------------
// Kernel 2: two-pass top-K, 64 scanners x 8 rows/thread.
//   Pass A: fp32 cosine scores; per-thread maxima over 49 disjoint cols/row.
//           theta[row] = 9th-largest of the 64 thread maxima - EPS
//           (>=9 distinct non-self cols >= theta => top-8 all >= theta).
//   Pass B: recompute scores; collect cols >= theta (u16, ~10-20 per row).
//   Pass C: fp64 re-rank (exact; validated R2/R3/R5) -> top-8 + self, sorted.
// Block: 256 threads = 4 row-groups(ig, 8 rows each) x 64 scanners(j).
// Thread computes RT=8 rows x MT=2 cols (j, j+64) per 128-col tile.
// Rows broadcast from rowbuf (uniform across j); cols stride-36 (2-way/phase).
// ---------------------------------------------------------------------------
__global__ __launch_bounds__(256, 4) void topk_kernel(
    const float* __restrict__ xnT, const float* __restrict__ xfT,
    const double* __restrict__ invn, int* __restrict__ idxo)
{
    __shared__ __align__(16) float colbuf[BC * 36];   // 18.4 KB (pass C: f64 scorebuf)
    __shared__ __align__(16) float rowbuf[BR * 36];   // 4.6 KB
    __shared__ uint16_t candidx[BR * CAP];            // 3.6 KB
    __shared__ int cnt[BR];

    int tid   = threadIdx.x;
    int b     = blockIdx.y;
    int browg = blockIdx.x * BR;
    size_t bbase = (size_t)b * TT;

    int ig = tid >> 6;       // row group 0..3 (8 rows each)
    int j  = tid & 63;       // col scanner 0..63

    // stage the block's 32 row vectors (one float4 per thread)
    {
        int row = tid >> 3, part = tid & 7;
        *(float4*)&rowbuf[row * 36 + part * 4] =
            *(const float4*)&xnT[(bbase + browg + row) * CC + part * 4];
    }
    if (tid < BR) cnt[tid] = 0;

    float acc[RT][MT];

    // ---------------- pass A: per-thread row maxima ----------------
    float mseg[RT];
#pragma unroll
    for (int r = 0; r < RT; ++r) mseg[r] = NEGINF;

    for (int tt = 0; tt < NTILE; ++tt) {
        int ct0 = tt * BC;
        int ccn = (ct0 + BC <= TT) ? BC : (TT - ct0);
        int mm  = ccn >> 6;          // 2 full / 1 runt
        __syncthreads();
        for (int g = tid; g < ccn * 8; g += 256) {
            int col = g >> 3, part = g & 7;
            *(float4*)&colbuf[col * 36 + part * 4] =
                *(const float4*)&xnT[(bbase + ct0 + col) * CC + part * 4];
        }
        __syncthreads();

#pragma unroll
        for (int r = 0; r < RT; ++r)
#pragma unroll
            for (int m = 0; m < MT; ++m) acc[r][m] = 0.f;

#pragma unroll
        for (int cq = 0; cq < 8; ++cq) {
            float4 a[RT];
#pragma unroll
            for (int r = 0; r < RT; ++r)
                a[r] = *(const float4*)&rowbuf[(ig*RT + r) * 36 + cq * 4];
#pragma unroll
            for (int m = 0; m < MT; ++m) {
                if (m < mm) {
                    float4 bv = *(const float4*)&colbuf[(j + 64*m) * 36 + cq * 4];
#pragma unroll
                    for (int r = 0; r < RT; ++r) {
                        acc[r][m] = fmaf(a[r].x, bv.x, acc[r][m]);
                        acc[r][m] = fmaf(a[r].y, bv.y, acc[r][m]);
                        acc[r][m] = fmaf(a[r].z, bv.z, acc[r][m]);
                        acc[r][m] = fmaf(a[r].w, bv.w, acc[r][m]);
                    }
                }
            }
        }

#pragma unroll
        for (int r = 0; r < RT; ++r) {
            int rowg = browg + ig*RT + r;
#pragma unroll
            for (int m = 0; m < MT; ++m) {
                if (m < mm) {
                    int col = ct0 + j + 64*m;
                    float v = (col == rowg) ? NEGINF : acc[r][m];
                    mseg[r] = fmaxf(mseg[r], v);
                }
            }
        }
    }

    // ---- theta: 9th-largest of 64 thread maxima, per row (full-wave shfl) ----
    int lane = tid & 63;
    float th[RT];
#pragma unroll
    for (int r = 0; r < RT; ++r) {
        uint32_t key = f2s(mseg[r]);
        uint32_t nth = 0;
        for (int round = 0; round < 9; ++round) {
            uint32_t m = key;
#pragma unroll
            for (int d = 1; d < 64; d <<= 1) {
                uint32_t o = (uint32_t)__shfl_xor((int)m, d, 64);
                m = (o > m) ? o : m;
            }
            nth = m;                           // round 8 -> 9th largest
            unsigned long long bal = __ballot(key == m);
            int leader = __ffsll(bal) - 1;
            if (lane == leader) key = 0;       // consume current max
        }
        th[r] = s2f(nth) - EPS;
    }

    // ---------------- pass B: collect candidates >= theta ----------------
    for (int tt = 0; tt < NTILE; ++tt) {
        int ct0 = tt * BC;
        int ccn = (ct0 + BC <= TT) ? BC : (TT - ct0);
        int mm  = ccn >> 6;
        __syncthreads();
        for (int g = tid; g < ccn * 8; g += 256) {
            int col = g >> 3, part = g & 7;
            *(float4*)&colbuf[col * 36 + part * 4] =
                *(const float4*)&xnT[(bbase + ct0 + col) * CC + part * 4];
        }
        __syncthreads();

#pragma unroll
        for (int r = 0; r < RT; ++r)
#pragma unroll
            for (int m = 0; m < MT; ++m) acc[r][m] = 0.f;

#pragma unroll
        for (int cq = 0; cq < 8; ++cq) {
            float4 a[RT];
#pragma unroll
            for (int r = 0; r < RT; ++r)
                a[r] = *(const float4*)&rowbuf[(ig*RT + r) * 36 + cq * 4];
#pragma unroll
            for (int m = 0; m < MT; ++m) {
                if (m < mm) {
                    float4 bv = *(const float4*)&colbuf[(j + 64*m) * 36 + cq * 4];
#pragma unroll
                    for (int r = 0; r < RT; ++r) {
                        acc[r][m] = fmaf(a[r].x, bv.x, acc[r][m]);
                        acc[r][m] = fmaf(a[r].y, bv.y, acc[r][m]);
                        acc[r][m] = fmaf(a[r].z, bv.z, acc[r][m]);
                        acc[r][m] = fmaf(a[r].w, bv.w, acc[r][m]);
                    }
                }
            }
        }

#pragma unroll
        for (int r = 0; r < RT; ++r) {
            int rowl = ig*RT + r;
            int rowg = browg + rowl;
#pragma unroll
            for (int m = 0; m < MT; ++m) {
                if (m < mm) {
                    int col = ct0 + j + 64*m;
                    float v = (col == rowg) ? NEGINF : acc[r][m];
                    if (v >= th[r]) {
                        int n = atomicAdd(&cnt[rowl], 1);
                        if (n < CAP) candidx[rowl * CAP + n] = (uint16_t)col;
                    }
                }
            }
        }
    }
    __syncthreads();

    // ---------------- pass C: fp64 exact re-rank ----------------
    double* scorebuf = (double*)colbuf;   // colbuf dead; 32*56*8 = 14336 B
    for (int g = tid; g < BR * CAP; g += 256) {
        int row  = g / CAP;
        int slot = g - row * CAP;
        int n = min(cnt[row], CAP);
        if (slot < n) {
            int s = (int)candidx[row * CAP + slot];
            const float* xt = xfT + (bbase + browg + row) * CC;
            const float* xs = xfT + (bbase + s) * CC;
            double a2 = 0.0;
#pragma unroll
            for (int c = 0; c < CC; c += 4) {
                float4 xtv = *(const float4*)(xt + c);
                float4 xsv = *(const float4*)(xs + c);
                a2 = fma((double)xtv.x, (double)xsv.x, a2);
                a2 = fma((double)xtv.y, (double)xsv.y, a2);
                a2 = fma((double)xtv.z, (double)xsv.z, a2);
                a2 = fma((double)xtv.w, (double)xsv.w, a2);
            }
            scorebuf[row * CAP + slot] = a2 * invn[bbase + s];
        }
    }
    __syncthreads();

    if ((tid & 7) == 0) {
        int row = tid >> 3;
        int t   = browg + row;
        int n   = min(cnt[row], CAP);
        double v8[8]; int i8[8];
#pragma unroll
        for (int jj = 0; jj < 8; ++jj) { v8[jj] = -1.0e300; i8[jj] = 0x7FFFFFFF; }
        for (int sl = 0; sl < n; ++sl) {
            double scr = scorebuf[row * CAP + sl];
            int    idx = (int)candidx[row * CAP + sl];
            bool better7 = (scr > v8[7]) || (scr == v8[7] && idx < i8[7]);
            if (better7) {
#pragma unroll
                for (int jj = 7; jj >= 1; --jj) {
                    bool up   = (scr > v8[jj-1]) || (scr == v8[jj-1] && idx < i8[jj-1]);
                    bool here = ((scr > v8[jj]) || (scr == v8[jj] && idx < i8[jj])) && !up;
                    v8[jj] = up ? v8[jj-1] : (here ? scr : v8[jj]);
                    i8[jj] = up ? i8[jj-1] : (here ? idx : i8[jj]);
                }
                bool top = (scr > v8[0]) || (scr == v8[0] && idx < i8[0]);
                if (top) { v8[0] = scr; i8[0] = idx; }
            }
        }
        int oi[9];
#pragma unroll
        for (int jj = 0; jj < 8; ++jj)
            oi[jj] = (i8[jj] == 0x7FFFFFFF) ? t : i8[jj];   // safety, never fires
        oi[8] = t;   // self (sim forced 1.1 -> always top-1)
        for (int a = 1; a < 9; ++a) {
            int kv = oi[a]; int jj = a - 1;
            while (jj >= 0 && oi[jj] > kv) { oi[jj+1] = oi[jj]; --jj; }
            oi[jj+1] = kv;
        }
        int* op = idxo + (bbase + t) * KK;
#pragma unroll
        for (int m = 0; m < 9; ++m) op[m] = oi[m];
    }
}

// ---------------------------------------------------------------------------
// Kernel 3: gather + conv1d(kernel=K, stride=K).  (validated R5, absmax 0)
// ---------------------------------------------------------------------------
__global__ __launch_bounds__(256) void gconv_kernel(
    const float* __restrict__ xfT, const int* __restrict__ idxi,
    const float* __restrict__ Wt, float* __restrict__ out)
{
    __shared__ float wl[288 * 65];
    __shared__ float ot[4][64 * 17];

    int tid = threadIdx.x;
    int b   = blockIdx.y;
    int t0  = blockIdx.x * 64;
    size_t bbase = (size_t)b * TT;

    for (int f = tid; f < OC * 288; f += 256) {
        int o  = f / 288;
        int ck = f - o * 288;
        wl[ck * 65 + o] = Wt[f];
    }
    __syncthreads();

    int w    = tid >> 6;
    int lane = tid & 63;        // = output channel o
    int tw0  = t0 + w * 16;

    for (int i0 = 0; i0 < 16; i0 += 4) {
        float a0 = 0.f, a1 = 0.f, a2 = 0.f, a3 = 0.f;
        const int* ip0 = idxi + (bbase + tw0 + i0) * KK;
#pragma unroll
        for (int k = 0; k < KK; ++k) {
            int s0 = __builtin_amdgcn_readfirstlane(ip0[0*KK + k]);
            int s1 = __builtin_amdgcn_readfirstlane(ip0[1*KK + k]);
            int s2 = __builtin_amdgcn_readfirstlane(ip0[2*KK + k]);
            int s3 = __builtin_amdgcn_readfirstlane(ip0[3*KK + k]);
            const float* c0 = xfT + (bbase + s0) * CC;
            const float* c1 = xfT + (bbase + s1) * CC;
            const float* c2 = xfT + (bbase + s2) * CC;
            const float* c3 = xfT + (bbase + s3) * CC;
#pragma unroll
            for (int c4 = 0; c4 < 8; ++c4) {
                float4 x0 = *(const float4*)(c0 + c4*4);
                float4 x1 = *(const float4*)(c1 + c4*4);
                float4 x2 = *(const float4*)(c2 + c4*4);
                float4 x3 = *(const float4*)(c3 + c4*4);
                float w0 = wl[((c4*4+0)*9 + k)*65 + lane];
                float w1 = wl[((c4*4+1)*9 + k)*65 + lane];
                float w2 = wl[((c4*4+2)*9 + k)*65 + lane];
                float w3 = wl[((c4*4+3)*9 + k)*65 + lane];
                a0 = fmaf(x0.x, w0, a0); a0 = fmaf(x0.y, w1, a0);
                a0 = fmaf(x0.z, w2, a0); a0 = fmaf(x0.w, w3, a0);
                a1 = fmaf(x1.x, w0, a1); a1 = fmaf(x1.y, w1, a1);
                a1 = fmaf(x1.z, w2, a1); a1 = fmaf(x1.w, w3, a1);
                a2 = fmaf(x2.x, w0, a2); a2 = fmaf(x2.y, w1, a2);
                a2 = fmaf(x2.z, w2, a2); a2 = fmaf(x2.w, w3, a2);
                a3 = fmaf(x3.x, w0, a3); a3 = fmaf(x3.y, w1, a3);
                a3 = fmaf(x3.z, w2, a3); a3 = fmaf(x3.w, w3, a3);
            }
        }
        ot[w][lane * 17 + i0 + 0] = a0;
        ot[w][lane * 17 + i0 + 1] = a1;
        ot[w][lane * 17 + i0 + 2] = a2;
        ot[w][lane * 17 + i0 + 3] = a3;
    }
    __syncthreads();

    for (int jj = 0; jj < 16; ++jj) {
        int fl = jj * 64 + lane;
        int o  = fl >> 4;
        int ii = fl & 15;
        out[((size_t)b * OC + o) * TT + tw0 + ii] = ot[w][o * 17 + ii];
    }
}

// ---------------------------------------------------------------------------
extern "C" void kernel_launch(void* const* d_in, const int* in_sizes, int n_in,
                              void* d_out, int out_size, void* d_ws, size_t ws_size,
                              hipStream_t stream)
{
    const float* x  = (const float*)d_in[0];   // [8][32][56][56]
    const float* Wt = (const float*)d_in[1];   // [64][32][9]
    float* out = (float*)d_out;                // [8][64][56][56]

    // workspace: xnT (fp32) | xfT (fp32) | invn (fp64) | idx (int)
    float*  xnT  = (float*)d_ws;
    float*  xfT  = xnT + (size_t)BB * TT * CC;
    double* invn = (double*)(xfT + (size_t)BB * TT * CC);
    int*    idw  = (int*)(invn + (size_t)BB * TT);

    dim3 g1((TT + 255) / 256, BB);
    norm_kernel<<<g1, 256, 0, stream>>>(x, xnT, xfT, invn);

    dim3 g2(TT / BR, BB);    // 98 x 8 = 784 blocks
    topk_kernel<<<g2, 256, 0, stream>>>(xnT, xfT, invn, idw);

    dim3 g3(TT / 64, BB);    // 49 x 8 = 392 blocks
    gconv_kernel<<<g3, 256, 0, stream>>>(xfT, idw, Wt, out);
}

// Round 7
// 1182.566 us; speedup vs baseline: 2.9854x; 2.9854x over previous
//
#include <hip/hip_runtime.h>
#include <stdint.h>
#include <math.h>

// Problem constants (from reference):
#define BB 8
#define CC 32
#define TT 3136      // 56*56
#define KK 9
#define OC 64

#define NEGINF (-3.0e38f)
#define BR 32        // rows per block
#define RT 8         // rows per thread (per scanner)
#define MT 4         // col accumulators per thread
#define BC 256       // cols per LDS tile
#define NTILE 13     // 12 full tiles + one 64-col runt
#define CAP 56       // candidate cap per row
#define EPS 1e-4f    // >= 2x fp32-vs-fp64 dot error (~1e-6); validated R5/R6

__device__ __forceinline__ uint32_t f2s(float v) {
    uint32_t u = __float_as_uint(v);
    return (u & 0x80000000u) ? ~u : (u | 0x80000000u);
}
__device__ __forceinline__ float s2f(uint32_t u) {
    u = (u & 0x80000000u) ? (u & 0x7FFFFFFFu) : ~u;
    return __uint_as_float(u);
}

// ---------------------------------------------------------------------------
// Kernel 1: transposed copies + norms.
// ---------------------------------------------------------------------------
__global__ __launch_bounds__(256) void norm_kernel(
    const float* __restrict__ x, float* __restrict__ xnT,
    float* __restrict__ xfT, double* __restrict__ invn)
{
    int t = blockIdx.x * 256 + threadIdx.x;
    int b = blockIdx.y;
    if (t >= TT) return;
    const float* xp = x + (size_t)b * CC * TT + t;
    float v[CC];
    double ss = 0.0;
#pragma unroll
    for (int c = 0; c < CC; ++c) {
        v[c] = xp[(size_t)c * TT];
        ss = fma((double)v[c], (double)v[c], ss);
    }
    double inv = 1.0 / fmax(sqrt(ss), 1e-12);
    invn[(size_t)b * TT + t] = inv;
    float invf = (float)inv;
    float* pf = xfT + ((size_t)b * TT + t) * CC;
    float* pn = xnT + ((size_t)b * TT + t) * CC;
#pragma unroll
    for (int c = 0; c < CC; c += 4) {
        *(float4*)(pf + c) = make_float4(v[c], v[c+1], v[c+2], v[c+3]);
        *(float4*)(pn + c) = make_float4(v[c]*invf, v[c+1]*invf, v[c+2]*invf, v[c+3]*invf);
    }
}

// ---------------------------------------------------------------------------
// One tile of the block-GEMM: RT=8 rows x MM cols per thread, acc in regs.
// PASSB=false: update per-thread row maxima (self-masked).
// PASSB=true : append cols with score >= th[r] (self-masked) to candidx.
// MM is compile-time (4 = full 256-col tile, 1 = 64-col runt) -> no runtime
// m-guards in the hot loop.
// ---------------------------------------------------------------------------
template<int MM, bool PASSB>
__device__ __forceinline__ void tile_gemm(
    const float* __restrict__ colbuf, const float* __restrict__ rowbuf,
    int ig, int j, int ct0, int browg,
    float (&mseg)[RT], const float (&th)[RT],
    uint16_t* __restrict__ candidx, int* __restrict__ cnt)
{
    float acc[RT][MM];
#pragma unroll
    for (int r = 0; r < RT; ++r)
#pragma unroll
        for (int m = 0; m < MM; ++m) acc[r][m] = 0.f;

#pragma unroll
    for (int cq = 0; cq < 8; ++cq) {
        float4 bv[MM];
#pragma unroll
        for (int m = 0; m < MM; ++m)
            bv[m] = *(const float4*)&colbuf[(j + 64*m) * 36 + cq * 4];
#pragma unroll
        for (int r = 0; r < RT; ++r) {
            float4 a = *(const float4*)&rowbuf[(ig*RT + r) * 36 + cq * 4];
#pragma unroll
            for (int m = 0; m < MM; ++m) {
                acc[r][m] = fmaf(a.x, bv[m].x, acc[r][m]);
                acc[r][m] = fmaf(a.y, bv[m].y, acc[r][m]);
                acc[r][m] = fmaf(a.z, bv[m].z, acc[r][m]);
                acc[r][m] = fmaf(a.w, bv[m].w, acc[r][m]);
            }
        }
    }

#pragma unroll
    for (int r = 0; r < RT; ++r) {
        int rowl = ig*RT + r;
        int rowg = browg + rowl;
        unsigned rel = (unsigned)(rowg - ct0);
        if (!PASSB) {
            if (rel < (unsigned)(64*MM)) {
                // rare: this tile contains the row itself -> mask it
#pragma unroll
                for (int m = 0; m < MM; ++m) {
                    float v = ((unsigned)(j + 64*m) == rel) ? NEGINF : acc[r][m];
                    mseg[r] = fmaxf(mseg[r], v);
                }
            } else {
#pragma unroll
                for (int m = 0; m < MM; ++m)
                    mseg[r] = fmaxf(mseg[r], acc[r][m]);
            }
        } else {
#pragma unroll
            for (int m = 0; m < MM; ++m) {
                float v = ((unsigned)(j + 64*m) == rel) ? NEGINF : acc[r][m];
                if (v >= th[r]) {
                    int n = atomicAdd(&cnt[rowl], 1);
                    if (n < CAP) candidx[rowl * CAP + n] = (uint16_t)(ct0 + j + 64*m);
                }
            }
        }
    }
}

// ---------------------------------------------------------------------------
// Kernel 2: two-pass top-K.
//   Pass A: fp32 cosine scores; per-thread maxima (49 disjoint cols/row);
//           theta[row] = 9th-largest of 64 thread maxima - EPS.
//   Pass B: recompute; collect cols >= theta (u16, ~10-20/row, CAP 56).
//   Pass C: fp64 re-rank (exact; validated R2/R3/R5/R6) -> top-8+self sorted.
// Block: 256 threads = 4 row-groups(ig) x 64 scanners(j); RT=8 x MT=4.
// ---------------------------------------------------------------------------
__global__ __launch_bounds__(256) void topk_kernel(
    const float* __restrict__ xnT, const float* __restrict__ xfT,
    const double* __restrict__ invn, int* __restrict__ idxo)
{
    __shared__ __align__(16) float colbuf[BC * 36];   // 36.9 KB (pass C: f64 scorebuf)
    __shared__ __align__(16) float rowbuf[BR * 36];   // 4.6 KB
    __shared__ uint16_t candidx[BR * CAP];            // 3.6 KB
    __shared__ int cnt[BR];

    int tid   = threadIdx.x;
    int b     = blockIdx.y;
    int browg = blockIdx.x * BR;
    size_t bbase = (size_t)b * TT;

    int ig = tid >> 6;       // row group 0..3 (8 rows each)
    int j  = tid & 63;       // col scanner 0..63

    // stage the block's 32 row vectors (one float4 per thread)
    {
        int row = tid >> 3, part = tid & 7;
        *(float4*)&rowbuf[row * 36 + part * 4] =
            *(const float4*)&xnT[(bbase + browg + row) * CC + part * 4];
    }
    if (tid < BR) cnt[tid] = 0;

    float mseg[RT];
    float th[RT];
#pragma unroll
    for (int r = 0; r < RT; ++r) { mseg[r] = NEGINF; th[r] = 0.f; }

    // ---------------- pass A ----------------
    for (int tt = 0; tt < NTILE; ++tt) {
        int ct0 = tt * BC;
        int ccn = (ct0 + BC <= TT) ? BC : (TT - ct0);
        __syncthreads();
        for (int g = tid; g < ccn * 8; g += 256) {
            int col = g >> 3, part = g & 7;
            *(float4*)&colbuf[col * 36 + part * 4] =
                *(const float4*)&xnT[(bbase + ct0 + col) * CC + part * 4];
        }
        __syncthreads();
        if (ccn == BC) tile_gemm<4, false>(colbuf, rowbuf, ig, j, ct0, browg, mseg, th, candidx, cnt);
        else           tile_gemm<1, false>(colbuf, rowbuf, ig, j, ct0, browg, mseg, th, candidx, cnt);
    }

    // ---- theta: 9th-largest of 64 thread maxima, per row (full-wave shfl) ----
    int lane = tid & 63;
#pragma unroll
    for (int r = 0; r < RT; ++r) {
        uint32_t key = f2s(mseg[r]);
        uint32_t nth = 0;
        for (int round = 0; round < 9; ++round) {
            uint32_t m = key;
#pragma unroll
            for (int d = 1; d < 64; d <<= 1) {
                uint32_t o = (uint32_t)__shfl_xor((int)m, d, 64);
                m = (o > m) ? o : m;
            }
            nth = m;                           // round 8 -> 9th largest
            unsigned long long bal = __ballot(key == m);
            int leader = __ffsll(bal) - 1;
            if (lane == leader) key = 0;       // consume current max
        }
        th[r] = s2f(nth) - EPS;
    }

    // ---------------- pass B ----------------
    for (int tt = 0; tt < NTILE; ++tt) {
        int ct0 = tt * BC;
        int ccn = (ct0 + BC <= TT) ? BC : (TT - ct0);
        __syncthreads();
        for (int g = tid; g < ccn * 8; g += 256) {
            int col = g >> 3, part = g & 7;
            *(float4*)&colbuf[col * 36 + part * 4] =
                *(const float4*)&xnT[(bbase + ct0 + col) * CC + part * 4];
        }
        __syncthreads();
        if (ccn == BC) tile_gemm<4, true>(colbuf, rowbuf, ig, j, ct0, browg, mseg, th, candidx, cnt);
        else           tile_gemm<1, true>(colbuf, rowbuf, ig, j, ct0, browg, mseg, th, candidx, cnt);
    }
    __syncthreads();

    // ---------------- pass C: fp64 exact re-rank ----------------
    double* scorebuf = (double*)colbuf;   // colbuf dead; 32*56*8 = 14336 B
    for (int g = tid; g < BR * CAP; g += 256) {
        int row  = g / CAP;
        int slot = g - row * CAP;
        int n = min(cnt[row], CAP);
        if (slot < n) {
            int s = (int)candidx[row * CAP + slot];
            const float* xt = xfT + (bbase + browg + row) * CC;
            const float* xs = xfT + (bbase + s) * CC;
            double a2 = 0.0;
#pragma unroll
            for (int c = 0; c < CC; c += 4) {
                float4 xtv = *(const float4*)(xt + c);
                float4 xsv = *(const float4*)(xs + c);
                a2 = fma((double)xtv.x, (double)xsv.x, a2);
                a2 = fma((double)xtv.y, (double)xsv.y, a2);
                a2 = fma((double)xtv.z, (double)xsv.z, a2);
                a2 = fma((double)xtv.w, (double)xsv.w, a2);
            }
            scorebuf[row * CAP + slot] = a2 * invn[bbase + s];
        }
    }
    __syncthreads();

    if ((tid & 7) == 0) {
        int row = tid >> 3;
        int t   = browg + row;
        int n   = min(cnt[row], CAP);
        double v8[8]; int i8[8];
#pragma unroll
        for (int jj = 0; jj < 8; ++jj) { v8[jj] = -1.0e300; i8[jj] = 0x7FFFFFFF; }
        for (int sl = 0; sl < n; ++sl) {
            double scr = scorebuf[row * CAP + sl];
            int    idx = (int)candidx[row * CAP + sl];
            bool better7 = (scr > v8[7]) || (scr == v8[7] && idx < i8[7]);
            if (better7) {
#pragma unroll
                for (int jj = 7; jj >= 1; --jj) {
                    bool up   = (scr > v8[jj-1]) || (scr == v8[jj-1] && idx < i8[jj-1]);
                    bool here = ((scr > v8[jj]) || (scr == v8[jj] && idx < i8[jj])) && !up;
                    v8[jj] = up ? v8[jj-1] : (here ? scr : v8[jj]);
                    i8[jj] = up ? i8[jj-1] : (here ? idx : i8[jj]);
                }
                bool top = (scr > v8[0]) || (scr == v8[0] && idx < i8[0]);
                if (top) { v8[0] = scr; i8[0] = idx; }
            }
        }
        int oi[9];
#pragma unroll
        for (int jj = 0; jj < 8; ++jj)
            oi[jj] = (i8[jj] == 0x7FFFFFFF) ? t : i8[jj];   // safety, never fires
        oi[8] = t;   // self (sim forced 1.1 -> always top-1)
        for (int a = 1; a < 9; ++a) {
            int kv = oi[a]; int jj = a - 1;
            while (jj >= 0 && oi[jj] > kv) { oi[jj+1] = oi[jj]; --jj; }
            oi[jj+1] = kv;
        }
        int* op = idxo + (bbase + t) * KK;
#pragma unroll
        for (int m = 0; m < 9; ++m) op[m] = oi[m];
    }
}

// ---------------------------------------------------------------------------
// Kernel 3: gather + conv1d(kernel=K, stride=K).  (validated R5/R6, absmax 0)
// ---------------------------------------------------------------------------
__global__ __launch_bounds__(256) void gconv_kernel(
    const float* __restrict__ xfT, const int* __restrict__ idxi,
    const float* __restrict__ Wt, float* __restrict__ out)
{
    __shared__ float wl[288 * 65];
    __shared__ float ot[4][64 * 17];

    int tid = threadIdx.x;
    int b   = blockIdx.y;
    int t0  = blockIdx.x * 64;
    size_t bbase = (size_t)b * TT;

    for (int f = tid; f < OC * 288; f += 256) {
        int o  = f / 288;
        int ck = f - o * 288;
        wl[ck * 65 + o] = Wt[f];
    }
    __syncthreads();

    int w    = tid >> 6;
    int lane = tid & 63;        // = output channel o
    int tw0  = t0 + w * 16;

    for (int i0 = 0; i0 < 16; i0 += 4) {
        float a0 = 0.f, a1 = 0.f, a2 = 0.f, a3 = 0.f;
        const int* ip0 = idxi + (bbase + tw0 + i0) * KK;
#pragma unroll
        for (int k = 0; k < KK; ++k) {
            int s0 = __builtin_amdgcn_readfirstlane(ip0[0*KK + k]);
            int s1 = __builtin_amdgcn_readfirstlane(ip0[1*KK + k]);
            int s2 = __builtin_amdgcn_readfirstlane(ip0[2*KK + k]);
            int s3 = __builtin_amdgcn_readfirstlane(ip0[3*KK + k]);
            const float* c0 = xfT + (bbase + s0) * CC;
            const float* c1 = xfT + (bbase + s1) * CC;
            const float* c2 = xfT + (bbase + s2) * CC;
            const float* c3 = xfT + (bbase + s3) * CC;
#pragma unroll
            for (int c4 = 0; c4 < 8; ++c4) {
                float4 x0 = *(const float4*)(c0 + c4*4);
                float4 x1 = *(const float4*)(c1 + c4*4);
                float4 x2 = *(const float4*)(c2 + c4*4);
                float4 x3 = *(const float4*)(c3 + c4*4);
                float w0 = wl[((c4*4+0)*9 + k)*65 + lane];
                float w1 = wl[((c4*4+1)*9 + k)*65 + lane];
                float w2 = wl[((c4*4+2)*9 + k)*65 + lane];
                float w3 = wl[((c4*4+3)*9 + k)*65 + lane];
                a0 = fmaf(x0.x, w0, a0); a0 = fmaf(x0.y, w1, a0);
                a0 = fmaf(x0.z, w2, a0); a0 = fmaf(x0.w, w3, a0);
                a1 = fmaf(x1.x, w0, a1); a1 = fmaf(x1.y, w1, a1);
                a1 = fmaf(x1.z, w2, a1); a1 = fmaf(x1.w, w3, a1);
                a2 = fmaf(x2.x, w0, a2); a2 = fmaf(x2.y, w1, a2);
                a2 = fmaf(x2.z, w2, a2); a2 = fmaf(x2.w, w3, a2);
                a3 = fmaf(x3.x, w0, a3); a3 = fmaf(x3.y, w1, a3);
                a3 = fmaf(x3.z, w2, a3); a3 = fmaf(x3.w, w3, a3);
            }
        }
        ot[w][lane * 17 + i0 + 0] = a0;
        ot[w][lane * 17 + i0 + 1] = a1;
        ot[w][lane * 17 + i0 + 2] = a2;
        ot[w][lane * 17 + i0 + 3] = a3;
    }
    __syncthreads();

    for (int jj = 0; jj < 16; ++jj) {
        int fl = jj * 64 + lane;
        int o  = fl >> 4;
        int ii = fl & 15;
        out[((size_t)b * OC + o) * TT + tw0 + ii] = ot[w][o * 17 + ii];
    }
}

// ---------------------------------------------------------------------------
extern "C" void kernel_launch(void* const* d_in, const int* in_sizes, int n_in,
                              void* d_out, int out_size, void* d_ws, size_t ws_size,
                              hipStream_t stream)
{
    const float* x  = (const float*)d_in[0];   // [8][32][56][56]
    const float* Wt = (const float*)d_in[1];   // [64][32][9]
    float* out = (float*)d_out;                // [8][64][56][56]

    // workspace: xnT (fp32) | xfT (fp32) | invn (fp64) | idx (int)
    float*  xnT  = (float*)d_ws;
    float*  xfT  = xnT + (size_t)BB * TT * CC;
    double* invn = (double*)(xfT + (size_t)BB * TT * CC);
    int*    idw  = (int*)(invn + (size_t)BB * TT);

    dim3 g1((TT + 255) / 256, BB);
    norm_kernel<<<g1, 256, 0, stream>>>(x, xnT, xfT, invn);

    dim3 g2(TT / BR, BB);    // 98 x 8 = 784 blocks
    topk_kernel<<<g2, 256, 0, stream>>>(xnT, xfT, invn, idw);

    dim3 g3(TT / 64, BB);    // 49 x 8 = 392 blocks
    gconv_kernel<<<g3, 256, 0, stream>>>(xfT, idw, Wt, out);
}

// Round 8
// 1178.880 us; speedup vs baseline: 2.9947x; 1.0031x over previous
//
#include <hip/hip_runtime.h>
#include <stdint.h>
#include <math.h>

// Problem constants (from reference):
#define BB 8
#define CC 32
#define TT 3136      // 56*56
#define TTP 3328     // padded to 13*256 (pad rows zeroed, masked from results)
#define KK 9
#define OC 64

#define NEGINF (-3.0e38f)
#define BR 16        // rows per block
#define RT 4         // rows per thread (per scanner)
#define MM 4         // col accumulators per thread
#define BC 256       // cols per LDS tile
#define NTILE 13     // TTP / BC, all full
#define CAP 64       // candidate cap per row
#define EPS 1e-4f    // >= 100x fp32-vs-fp64 dot error; validated R5/R6/R7

__device__ __forceinline__ uint32_t f2s(float v) {
    uint32_t u = __float_as_uint(v);
    return (u & 0x80000000u) ? ~u : (u | 0x80000000u);
}
__device__ __forceinline__ float s2f(uint32_t u) {
    u = (u & 0x80000000u) ? (u & 0x7FFFFFFFu) : ~u;
    return __uint_as_float(u);
}

// ---------------------------------------------------------------------------
// Kernel 1: transposed copies + norms; zero-fills xnT pad rows [TT, TTP).
// ---------------------------------------------------------------------------
__global__ __launch_bounds__(256) void norm_kernel(
    const float* __restrict__ x, float* __restrict__ xnT,
    float* __restrict__ xfT, double* __restrict__ invn)
{
    int t = blockIdx.x * 256 + threadIdx.x;
    int b = blockIdx.y;
    if (t >= TTP) return;
    float* pn = xnT + ((size_t)b * TTP + t) * CC;
    if (t >= TT) {   // pad rows: zero (masked in topk anyway, but keep defined)
#pragma unroll
        for (int c = 0; c < CC; c += 4)
            *(float4*)(pn + c) = make_float4(0.f, 0.f, 0.f, 0.f);
        return;
    }
    const float* xp = x + (size_t)b * CC * TT + t;
    float v[CC];
    double ss = 0.0;
#pragma unroll
    for (int c = 0; c < CC; ++c) {
        v[c] = xp[(size_t)c * TT];
        ss = fma((double)v[c], (double)v[c], ss);
    }
    double inv = 1.0 / fmax(sqrt(ss), 1e-12);
    invn[(size_t)b * TT + t] = inv;
    float invf = (float)inv;
    float* pf = xfT + ((size_t)b * TT + t) * CC;
#pragma unroll
    for (int c = 0; c < CC; c += 4) {
        *(float4*)(pf + c) = make_float4(v[c], v[c+1], v[c+2], v[c+3]);
        *(float4*)(pn + c) = make_float4(v[c]*invf, v[c+1]*invf, v[c+2]*invf, v[c+3]*invf);
    }
}

// ---------------------------------------------------------------------------
// Kernel 2a: pass A — fp32 cosine scores, per-thread row maxima over 52
// disjoint cols, theta[row] = 9th-largest of the 64 per-lane maxima - EPS.
// Block: 256 thr = 4 waves(ig = 4 rows each) x 64 scanners(j). RT=4 x MM=4.
// ---------------------------------------------------------------------------
__global__ __launch_bounds__(256) void topk_a(
    const float* __restrict__ xnT, float* __restrict__ thbuf)
{
    __shared__ __align__(16) float colbuf[BC * 36];   // 36.9 KB
    __shared__ __align__(16) float rowbuf[BR * 36];   // 2.3 KB

    int tid   = threadIdx.x;
    int b     = blockIdx.y;
    int browg = blockIdx.x * BR;
    size_t bpad = (size_t)b * TTP;

    int ig = tid >> 6;       // wave / row group (0..3)
    int j  = tid & 63;       // scanner (0..63)

    if (tid < BR * 8) {
        int row = tid >> 3, part = tid & 7;
        *(float4*)&rowbuf[row * 36 + part * 4] =
            *(const float4*)&xnT[(bpad + browg + row) * CC + part * 4];
    }

    float mseg[RT];
#pragma unroll
    for (int r = 0; r < RT; ++r) mseg[r] = NEGINF;

    for (int tt = 0; tt < NTILE; ++tt) {
        int ct0 = tt * BC;
        __syncthreads();
        for (int g = tid; g < BC * 8; g += 256) {
            int col = g >> 3, part = g & 7;
            *(float4*)&colbuf[col * 36 + part * 4] =
                *(const float4*)&xnT[(bpad + ct0 + col) * CC + part * 4];
        }
        __syncthreads();

        float acc[RT][MM];
#pragma unroll
        for (int r = 0; r < RT; ++r)
#pragma unroll
            for (int m = 0; m < MM; ++m) acc[r][m] = 0.f;

#pragma unroll
        for (int cq = 0; cq < 8; ++cq) {
            float4 bv[MM];
#pragma unroll
            for (int m = 0; m < MM; ++m)
                bv[m] = *(const float4*)&colbuf[(j + 64*m) * 36 + cq * 4];
#pragma unroll
            for (int r = 0; r < RT; ++r) {
                float4 a = *(const float4*)&rowbuf[(ig*RT + r) * 36 + cq * 4];
#pragma unroll
                for (int m = 0; m < MM; ++m) {
                    acc[r][m] = fmaf(a.x, bv[m].x, acc[r][m]);
                    acc[r][m] = fmaf(a.y, bv[m].y, acc[r][m]);
                    acc[r][m] = fmaf(a.z, bv[m].z, acc[r][m]);
                    acc[r][m] = fmaf(a.w, bv[m].w, acc[r][m]);
                }
            }
        }

        int realm = (TT - ct0) >> 6;           // 4 for full tiles, 1 for last
#pragma unroll
        for (int r = 0; r < RT; ++r) {
            unsigned rel = (unsigned)(browg + ig*RT + r - ct0);
#pragma unroll
            for (int m = 0; m < MM; ++m) {
                float v = ((unsigned)(j + 64*m) == rel) ? NEGINF : acc[r][m];
                if (m < realm) mseg[r] = fmaxf(mseg[r], v);
            }
        }
    }

    // theta: 9th-largest of 64 per-lane maxima, per row (validated R6/R7)
#pragma unroll
    for (int r = 0; r < RT; ++r) {
        uint32_t key = f2s(mseg[r]);
        uint32_t nth = 0;
        for (int round = 0; round < 9; ++round) {
            uint32_t m = key;
#pragma unroll
            for (int d = 1; d < 64; d <<= 1) {
                uint32_t o = (uint32_t)__shfl_xor((int)m, d, 64);
                m = (o > m) ? o : m;
            }
            nth = m;
            unsigned long long bal = __ballot(key == m);
            int leader = __ffsll(bal) - 1;
            if (j == leader) key = 0;
        }
        if (j == 0)
            thbuf[(size_t)b * TT + browg + ig*RT + r] = s2f(nth) - EPS;
    }
}

// ---------------------------------------------------------------------------
// Kernel 2b: pass B — recompute scores (bit-identical fmaf chain), collect
// cols >= theta; pass C — fp64 exact re-rank -> top-8 + self, sorted.
// ---------------------------------------------------------------------------
__global__ __launch_bounds__(256) void topk_b(
    const float* __restrict__ xnT, const float* __restrict__ xfT,
    const double* __restrict__ invn, const float* __restrict__ thbuf,
    int* __restrict__ idxo)
{
    __shared__ __align__(16) float colbuf[BC * 36];   // 36.9 KB (pass C: scorebuf)
    __shared__ __align__(16) float rowbuf[BR * 36];   // 2.3 KB
    __shared__ uint16_t candidx[BR * CAP];            // 2.0 KB
    __shared__ int cnt[BR];

    int tid   = threadIdx.x;
    int b     = blockIdx.y;
    int browg = blockIdx.x * BR;
    size_t bpad  = (size_t)b * TTP;
    size_t bbase = (size_t)b * TT;

    int ig = tid >> 6;
    int j  = tid & 63;

    if (tid < BR * 8) {
        int row = tid >> 3, part = tid & 7;
        *(float4*)&rowbuf[row * 36 + part * 4] =
            *(const float4*)&xnT[(bpad + browg + row) * CC + part * 4];
    }
    if (tid < BR) cnt[tid] = 0;

    float th[RT];
#pragma unroll
    for (int r = 0; r < RT; ++r)
        th[r] = thbuf[bbase + browg + ig*RT + r];

    for (int tt = 0; tt < NTILE; ++tt) {
        int ct0 = tt * BC;
        __syncthreads();
        for (int g = tid; g < BC * 8; g += 256) {
            int col = g >> 3, part = g & 7;
            *(float4*)&colbuf[col * 36 + part * 4] =
                *(const float4*)&xnT[(bpad + ct0 + col) * CC + part * 4];
        }
        __syncthreads();

        float acc[RT][MM];
#pragma unroll
        for (int r = 0; r < RT; ++r)
#pragma unroll
            for (int m = 0; m < MM; ++m) acc[r][m] = 0.f;

#pragma unroll
        for (int cq = 0; cq < 8; ++cq) {
            float4 bv[MM];
#pragma unroll
            for (int m = 0; m < MM; ++m)
                bv[m] = *(const float4*)&colbuf[(j + 64*m) * 36 + cq * 4];
#pragma unroll
            for (int r = 0; r < RT; ++r) {
                float4 a = *(const float4*)&rowbuf[(ig*RT + r) * 36 + cq * 4];
#pragma unroll
                for (int m = 0; m < MM; ++m) {
                    acc[r][m] = fmaf(a.x, bv[m].x, acc[r][m]);
                    acc[r][m] = fmaf(a.y, bv[m].y, acc[r][m]);
                    acc[r][m] = fmaf(a.z, bv[m].z, acc[r][m]);
                    acc[r][m] = fmaf(a.w, bv[m].w, acc[r][m]);
                }
            }
        }

        int realm = (TT - ct0) >> 6;
#pragma unroll
        for (int r = 0; r < RT; ++r) {
            int rowl = ig*RT + r;
            unsigned rel = (unsigned)(browg + rowl - ct0);
#pragma unroll
            for (int m = 0; m < MM; ++m) {
                float v = ((unsigned)(j + 64*m) == rel) ? NEGINF : acc[r][m];
                if (m < realm && v >= th[r]) {
                    int n = atomicAdd(&cnt[rowl], 1);
                    if (n < CAP) candidx[rowl * CAP + n] = (uint16_t)(ct0 + j + 64*m);
                }
            }
        }
    }
    __syncthreads();

    // ---------------- pass C: fp64 exact re-rank (validated R2..R7) --------
    double* scorebuf = (double*)colbuf;   // 16*64*8 = 8 KB <= colbuf
    for (int g = tid; g < BR * CAP; g += 256) {
        int row  = g >> 6;             // CAP = 64
        int slot = g & 63;
        int n = min(cnt[row], CAP);
        if (slot < n) {
            int s = (int)candidx[row * CAP + slot];
            const float* xt = xfT + (bbase + browg + row) * CC;
            const float* xs = xfT + (bbase + s) * CC;
            double a2 = 0.0;
#pragma unroll
            for (int c = 0; c < CC; c += 4) {
                float4 xtv = *(const float4*)(xt + c);
                float4 xsv = *(const float4*)(xs + c);
                a2 = fma((double)xtv.x, (double)xsv.x, a2);
                a2 = fma((double)xtv.y, (double)xsv.y, a2);
                a2 = fma((double)xtv.z, (double)xsv.z, a2);
                a2 = fma((double)xtv.w, (double)xsv.w, a2);
            }
            scorebuf[row * CAP + slot] = a2 * invn[bbase + s];
        }
    }
    __syncthreads();

    if ((tid & 15) == 0) {
        int row = tid >> 4;
        int t   = browg + row;
        int n   = min(cnt[row], CAP);
        double v8[8]; int i8[8];
#pragma unroll
        for (int jj = 0; jj < 8; ++jj) { v8[jj] = -1.0e300; i8[jj] = 0x7FFFFFFF; }
        for (int sl = 0; sl < n; ++sl) {
            double scr = scorebuf[row * CAP + sl];
            int    idx = (int)candidx[row * CAP + sl];
            bool better7 = (scr > v8[7]) || (scr == v8[7] && idx < i8[7]);
            if (better7) {
#pragma unroll
                for (int jj = 7; jj >= 1; --jj) {
                    bool up   = (scr > v8[jj-1]) || (scr == v8[jj-1] && idx < i8[jj-1]);
                    bool here = ((scr > v8[jj]) || (scr == v8[jj] && idx < i8[jj])) && !up;
                    v8[jj] = up ? v8[jj-1] : (here ? scr : v8[jj]);
                    i8[jj] = up ? i8[jj-1] : (here ? idx : i8[jj]);
                }
                bool top = (scr > v8[0]) || (scr == v8[0] && idx < i8[0]);
                if (top) { v8[0] = scr; i8[0] = idx; }
            }
        }
        int oi[9];
#pragma unroll
        for (int jj = 0; jj < 8; ++jj)
            oi[jj] = (i8[jj] == 0x7FFFFFFF) ? t : i8[jj];   // safety, never fires
        oi[8] = t;   // self (sim forced 1.1 -> always top-1)
        for (int a = 1; a < 9; ++a) {
            int kv = oi[a]; int jj = a - 1;
            while (jj >= 0 && oi[jj] > kv) { oi[jj+1] = oi[jj]; --jj; }
            oi[jj+1] = kv;
        }
        int* op = idxo + (bbase + t) * KK;
#pragma unroll
        for (int m = 0; m < 9; ++m) op[m] = oi[m];
    }
}

// ---------------------------------------------------------------------------
// Kernel 3: gather + conv1d(kernel=K, stride=K).
//   out[b][o][t] = sum_{k,c} W[o][c][k] * xfT[b][idx[b][t][k]][c]
// W staged as [k][c4][o][0..3] -> one ds_read_b128 per (k,c4), conflict-free.
// 4 t's per pass share each weight read; per-accumulator chain order
// identical to R3's validated kernel (k outer, c ascending, 4 chains).
// ---------------------------------------------------------------------------
__global__ __launch_bounds__(256) void gconv_kernel(
    const float* __restrict__ xfT, const int* __restrict__ idxi,
    const float* __restrict__ Wt, float* __restrict__ out)
{
    __shared__ float wl2[KK * 8 * 64 * 4];   // 73.7 KB: [k][c4][o][cc]
    __shared__ float ot[4][64 * 17];         // 17.4 KB

    int tid = threadIdx.x;
    int b   = blockIdx.y;
    int t0  = blockIdx.x * 64;
    size_t bbase = (size_t)b * TT;

    for (int f = tid; f < OC * 288; f += 256) {
        int o  = f / 288;
        int ck = f - o * 288;
        int c  = ck / KK;
        int k  = ck - c * KK;
        wl2[(((k*8 + (c >> 2)) * 64 + o) << 2) + (c & 3)] = Wt[f];
    }
    __syncthreads();

    int w    = tid >> 6;
    int lane = tid & 63;        // = output channel o
    int tw0  = t0 + w * 16;

    for (int i0 = 0; i0 < 16; i0 += 4) {
        float aa[4][4];
#pragma unroll
        for (int i = 0; i < 4; ++i)
#pragma unroll
            for (int q = 0; q < 4; ++q) aa[i][q] = 0.f;

        const int* ip0 = idxi + (bbase + tw0 + i0) * KK;
#pragma unroll
        for (int k = 0; k < KK; ++k) {
            int s0 = __builtin_amdgcn_readfirstlane(ip0[0*KK + k]);
            int s1 = __builtin_amdgcn_readfirstlane(ip0[1*KK + k]);
            int s2 = __builtin_amdgcn_readfirstlane(ip0[2*KK + k]);
            int s3 = __builtin_amdgcn_readfirstlane(ip0[3*KK + k]);
            const float* c0 = xfT + (bbase + s0) * CC;
            const float* c1 = xfT + (bbase + s1) * CC;
            const float* c2 = xfT + (bbase + s2) * CC;
            const float* c3 = xfT + (bbase + s3) * CC;
#pragma unroll
            for (int c4 = 0; c4 < 8; ++c4) {
                float4 wv = *(const float4*)&wl2[((k*8 + c4) * 64 + lane) << 2];
                int q = c4 & 3;
                float4 x0 = *(const float4*)(c0 + c4*4);
                aa[0][q] = fmaf(x0.x, wv.x, aa[0][q]); aa[0][q] = fmaf(x0.y, wv.y, aa[0][q]);
                aa[0][q] = fmaf(x0.z, wv.z, aa[0][q]); aa[0][q] = fmaf(x0.w, wv.w, aa[0][q]);
                float4 x1 = *(const float4*)(c1 + c4*4);
                aa[1][q] = fmaf(x1.x, wv.x, aa[1][q]); aa[1][q] = fmaf(x1.y, wv.y, aa[1][q]);
                aa[1][q] = fmaf(x1.z, wv.z, aa[1][q]); aa[1][q] = fmaf(x1.w, wv.w, aa[1][q]);
                float4 x2 = *(const float4*)(c2 + c4*4);
                aa[2][q] = fmaf(x2.x, wv.x, aa[2][q]); aa[2][q] = fmaf(x2.y, wv.y, aa[2][q]);
                aa[2][q] = fmaf(x2.z, wv.z, aa[2][q]); aa[2][q] = fmaf(x2.w, wv.w, aa[2][q]);
                float4 x3 = *(const float4*)(c3 + c4*4);
                aa[3][q] = fmaf(x3.x, wv.x, aa[3][q]); aa[3][q] = fmaf(x3.y, wv.y, aa[3][q]);
                aa[3][q] = fmaf(x3.z, wv.z, aa[3][q]); aa[3][q] = fmaf(x3.w, wv.w, aa[3][q]);
            }
        }
#pragma unroll
        for (int i = 0; i < 4; ++i)
            ot[w][lane * 17 + i0 + i] = (aa[i][0] + aa[i][1]) + (aa[i][2] + aa[i][3]);
    }
    __syncthreads();

    for (int jj = 0; jj < 16; ++jj) {
        int fl = jj * 64 + lane;
        int o  = fl >> 4;
        int ii = fl & 15;
        out[((size_t)b * OC + o) * TT + tw0 + ii] = ot[w][o * 17 + ii];
    }
}

// ---------------------------------------------------------------------------
extern "C" void kernel_launch(void* const* d_in, const int* in_sizes, int n_in,
                              void* d_out, int out_size, void* d_ws, size_t ws_size,
                              hipStream_t stream)
{
    const float* x  = (const float*)d_in[0];   // [8][32][56][56]
    const float* Wt = (const float*)d_in[1];   // [64][32][9]
    float* out = (float*)d_out;                // [8][64][56][56]

    // workspace: xnT (fp32, padded TTP) | xfT (fp32) | invn (fp64) | idx | thbuf
    float*  xnT  = (float*)d_ws;
    float*  xfT  = xnT + (size_t)BB * TTP * CC;
    double* invn = (double*)(xfT + (size_t)BB * TT * CC);
    int*    idw  = (int*)(invn + (size_t)BB * TT);
    float*  thb  = (float*)(idw + (size_t)BB * TT * KK);

    dim3 g1((TTP + 255) / 256, BB);
    norm_kernel<<<g1, 256, 0, stream>>>(x, xnT, xfT, invn);

    dim3 g2(TT / BR, BB);    // 196 x 8 = 1568 blocks
    topk_a<<<g2, 256, 0, stream>>>(xnT, thb);
    topk_b<<<g2, 256, 0, stream>>>(xnT, xfT, invn, thb, idw);

    dim3 g3(TT / 64, BB);    // 49 x 8 = 392 blocks
    gconv_kernel<<<g3, 256, 0, stream>>>(xfT, idw, Wt, out);
}

// Round 9
// 712.389 us; speedup vs baseline: 4.9558x; 1.6548x over previous
//
#include <hip/hip_runtime.h>
#include <stdint.h>
#include <math.h>

// Problem constants (from reference):
#define BB 8
#define CC 32
#define TT 3136      // 56*56
#define TTP 3328     // padded to 13*256 (pad rows zeroed, masked)
#define KK 9
#define OC 64

#define NEGINF (-3.0e38f)
#define BR 32        // rows per block
#define RT 8         // rows per thread (per scanner)
#define MM 4         // col accumulators per thread
#define BC 256       // cols per LDS tile
#define NTILE 13     // TTP / BC
#define CAP 64       // candidate cap per row
#define EPS 1e-4f    // >= 100x fp32-vs-fp64 dot error; validated R5..R8

__device__ __forceinline__ uint32_t f2s(float v) {
    uint32_t u = __float_as_uint(v);
    return (u & 0x80000000u) ? ~u : (u | 0x80000000u);
}
__device__ __forceinline__ float s2f(uint32_t u) {
    u = (u & 0x80000000u) ? (u & 0x7FFFFFFFu) : ~u;
    return __uint_as_float(u);
}

// ---------------------------------------------------------------------------
// Kernel 1: transposed copies + norms; zero-fills xnT pad rows [TT, TTP).
// ---------------------------------------------------------------------------
__global__ __launch_bounds__(256) void norm_kernel(
    const float* __restrict__ x, float* __restrict__ xnT,
    float* __restrict__ xfT, double* __restrict__ invn)
{
    int t = blockIdx.x * 256 + threadIdx.x;
    int b = blockIdx.y;
    if (t >= TTP) return;
    float* pn = xnT + ((size_t)b * TTP + t) * CC;
    if (t >= TT) {
#pragma unroll
        for (int c = 0; c < CC; c += 4)
            *(float4*)(pn + c) = make_float4(0.f, 0.f, 0.f, 0.f);
        return;
    }
    const float* xp = x + (size_t)b * CC * TT + t;
    float v[CC];
    double ss = 0.0;
#pragma unroll
    for (int c = 0; c < CC; ++c) {
        v[c] = xp[(size_t)c * TT];
        ss = fma((double)v[c], (double)v[c], ss);
    }
    double inv = 1.0 / fmax(sqrt(ss), 1e-12);
    invn[(size_t)b * TT + t] = inv;
    float invf = (float)inv;
    float* pf = xfT + ((size_t)b * TT + t) * CC;
#pragma unroll
    for (int c = 0; c < CC; c += 4) {
        *(float4*)(pf + c) = make_float4(v[c], v[c+1], v[c+2], v[c+3]);
        *(float4*)(pn + c) = make_float4(v[c]*invf, v[c+1]*invf, v[c+2]*invf, v[c+3]*invf);
    }
}

// ---------------------------------------------------------------------------
// Shared tile-GEMM body for topk_a / topk_b.
// colbufT: [cq=8][col=256] float4 (transposed) -> all LDS reads/writes are
// contiguous 1KB per wave-instr = conflict-free floor.
// sched_barrier(0) per cq bounds live LDS loads (anti-hoist; see R7/R8 VGPR).
// Chain order per (r,m) identical to R5..R8 -> bit-identical scores.
// ---------------------------------------------------------------------------

// stage one 256-col tile: thread tid owns column (ct0 + tid)
#define STAGE_TILE(dst, src, bpad, ct0)                                        \
    {                                                                          \
        const float4* gp = (const float4*)&(src)[((bpad) + (ct0) + tid) * CC]; \
        _Pragma("unroll")                                                      \
        for (int p = 0; p < 8; ++p) (dst)[p * 256 + tid] = gp[p];              \
    }

#define TILE_GEMM(accvar)                                                      \
    {                                                                          \
        _Pragma("unroll")                                                      \
        for (int r = 0; r < RT; ++r)                                           \
            _Pragma("unroll")                                                  \
            for (int m = 0; m < MM; ++m) accvar[r][m] = 0.f;                   \
        _Pragma("unroll")                                                      \
        for (int cq = 0; cq < 8; ++cq) {                                       \
            float4 bv[MM];                                                     \
            _Pragma("unroll")                                                  \
            for (int m = 0; m < MM; ++m)                                       \
                bv[m] = colbufT[cq * 256 + j + 64 * m];                        \
            _Pragma("unroll")                                                  \
            for (int r = 0; r < RT; ++r) {                                     \
                float4 a = *(const float4*)&rowbuf[(ig * RT + r) * CC + cq*4]; \
                _Pragma("unroll")                                              \
                for (int m = 0; m < MM; ++m) {                                 \
                    accvar[r][m] = fmaf(a.x, bv[m].x, accvar[r][m]);           \
                    accvar[r][m] = fmaf(a.y, bv[m].y, accvar[r][m]);           \
                    accvar[r][m] = fmaf(a.z, bv[m].z, accvar[r][m]);           \
                    accvar[r][m] = fmaf(a.w, bv[m].w, accvar[r][m]);           \
                }                                                              \
            }                                                                  \
            __builtin_amdgcn_sched_barrier(0);                                 \
        }                                                                      \
    }

// ---------------------------------------------------------------------------
// Kernel 2a: pass A — per-thread row maxima, theta = 9th-largest of the 64
// per-lane maxima - EPS  (>=9 distinct non-self cols >= theta).
// Block: 256 thr = 4 row-groups(ig, RT=8 rows) x 64 scanners(j).
// ---------------------------------------------------------------------------
__global__ __launch_bounds__(256) void topk_a(
    const float* __restrict__ xnT, float* __restrict__ thbuf)
{
    __shared__ __align__(16) float4 colbufT[8 * 256];   // 32 KB
    __shared__ __align__(16) float  rowbuf[BR * CC];    // 4 KB

    int tid   = threadIdx.x;
    int b     = blockIdx.y;
    int browg = blockIdx.x * BR;
    size_t bpad = (size_t)b * TTP;

    int ig = tid >> 6;
    int j  = tid & 63;

    {   // stage 32 row vectors
        int row = tid >> 3, part = tid & 7;
        *(float4*)&rowbuf[row * CC + part * 4] =
            *(const float4*)&xnT[(bpad + browg + row) * CC + part * 4];
    }

    float mseg[RT];
#pragma unroll
    for (int r = 0; r < RT; ++r) mseg[r] = NEGINF;

    for (int tt = 0; tt < NTILE; ++tt) {
        int ct0 = tt * BC;
        __syncthreads();
        STAGE_TILE(colbufT, xnT, bpad, ct0);
        __syncthreads();

        float acc[RT][MM];
        TILE_GEMM(acc);

        int realm = (TT - ct0) >> 6;    // 4 full, 1 on the last real tile
#pragma unroll
        for (int r = 0; r < RT; ++r) {
            unsigned rel = (unsigned)(browg + ig*RT + r - ct0);
#pragma unroll
            for (int m = 0; m < MM; ++m) {
                float v = ((unsigned)(j + 64*m) == rel) ? NEGINF : acc[r][m];
                if (m < realm) mseg[r] = fmaxf(mseg[r], v);
            }
        }
    }

    // theta: 9th-largest of 64 per-lane maxima (validated R6..R8)
#pragma unroll
    for (int r = 0; r < RT; ++r) {
        uint32_t key = f2s(mseg[r]);
        uint32_t nth = 0;
        for (int round = 0; round < 9; ++round) {
            uint32_t m = key;
#pragma unroll
            for (int d = 1; d < 64; d <<= 1) {
                uint32_t o = (uint32_t)__shfl_xor((int)m, d, 64);
                m = (o > m) ? o : m;
            }
            nth = m;
            unsigned long long bal = __ballot(key == m);
            int leader = __ffsll(bal) - 1;
            if (j == leader) key = 0;
        }
        if (j == 0)
            thbuf[(size_t)b * TT + browg + ig*RT + r] = s2f(nth) - EPS;
    }
}

// ---------------------------------------------------------------------------
// Kernel 2b: pass B — recompute (bit-identical), collect cols >= theta;
// pass C — fp64 exact re-rank -> top-8 + self, sorted ascending.
// ---------------------------------------------------------------------------
__global__ __launch_bounds__(256) void topk_b(
    const float* __restrict__ xnT, const float* __restrict__ xfT,
    const double* __restrict__ invn, const float* __restrict__ thbuf,
    int* __restrict__ idxo)
{
    __shared__ __align__(16) float4 colbufT[8 * 256];   // 32 KB (pass C: scorebuf)
    __shared__ __align__(16) float  rowbuf[BR * CC];    // 4 KB
    __shared__ uint16_t candidx[BR * CAP];              // 4 KB
    __shared__ int cnt[BR];

    int tid   = threadIdx.x;
    int b     = blockIdx.y;
    int browg = blockIdx.x * BR;
    size_t bpad  = (size_t)b * TTP;
    size_t bbase = (size_t)b * TT;

    int ig = tid >> 6;
    int j  = tid & 63;

    {
        int row = tid >> 3, part = tid & 7;
        *(float4*)&rowbuf[row * CC + part * 4] =
            *(const float4*)&xnT[(bpad + browg + row) * CC + part * 4];
    }
    if (tid < BR) cnt[tid] = 0;

    float th[RT];
#pragma unroll
    for (int r = 0; r < RT; ++r)
        th[r] = thbuf[bbase + browg + ig*RT + r];

    for (int tt = 0; tt < NTILE; ++tt) {
        int ct0 = tt * BC;
        __syncthreads();
        STAGE_TILE(colbufT, xnT, bpad, ct0);
        __syncthreads();

        float acc[RT][MM];
        TILE_GEMM(acc);

        int realm = (TT - ct0) >> 6;
#pragma unroll
        for (int r = 0; r < RT; ++r) {
            int rowl = ig*RT + r;
            unsigned rel = (unsigned)(browg + rowl - ct0);
#pragma unroll
            for (int m = 0; m < MM; ++m) {
                float v = ((unsigned)(j + 64*m) == rel) ? NEGINF : acc[r][m];
                if (m < realm && v >= th[r]) {
                    int n = atomicAdd(&cnt[rowl], 1);
                    if (n < CAP) candidx[rowl * CAP + n] = (uint16_t)(ct0 + j + 64*m);
                }
            }
        }
    }
    __syncthreads();

    // ---------------- pass C: fp64 exact re-rank (validated R2..R8) --------
    double* scorebuf = (double*)colbufT;   // 32*64*8 = 16 KB <= 32 KB
    for (int g = tid; g < BR * CAP; g += 256) {
        int row  = g >> 6;             // CAP = 64
        int slot = g & 63;
        int n = min(cnt[row], CAP);
        if (slot < n) {
            int s = (int)candidx[row * CAP + slot];
            const float* xt = xfT + (bbase + browg + row) * CC;
            const float* xs = xfT + (bbase + s) * CC;
            double a2 = 0.0;
#pragma unroll
            for (int c = 0; c < CC; c += 4) {
                float4 xtv = *(const float4*)(xt + c);
                float4 xsv = *(const float4*)(xs + c);
                a2 = fma((double)xtv.x, (double)xsv.x, a2);
                a2 = fma((double)xtv.y, (double)xsv.y, a2);
                a2 = fma((double)xtv.z, (double)xsv.z, a2);
                a2 = fma((double)xtv.w, (double)xsv.w, a2);
            }
            scorebuf[row * CAP + slot] = a2 * invn[bbase + s];
        }
    }
    __syncthreads();

    if ((tid & 7) == 0) {
        int row = tid >> 3;            // 0..31
        int t   = browg + row;
        int n   = min(cnt[row], CAP);
        double v8[8]; int i8[8];
#pragma unroll
        for (int jj = 0; jj < 8; ++jj) { v8[jj] = -1.0e300; i8[jj] = 0x7FFFFFFF; }
        for (int sl = 0; sl < n; ++sl) {
            double scr = scorebuf[row * CAP + sl];
            int    idx = (int)candidx[row * CAP + sl];
            bool better7 = (scr > v8[7]) || (scr == v8[7] && idx < i8[7]);
            if (better7) {
#pragma unroll
                for (int jj = 7; jj >= 1; --jj) {
                    bool up   = (scr > v8[jj-1]) || (scr == v8[jj-1] && idx < i8[jj-1]);
                    bool here = ((scr > v8[jj]) || (scr == v8[jj] && idx < i8[jj])) && !up;
                    v8[jj] = up ? v8[jj-1] : (here ? scr : v8[jj]);
                    i8[jj] = up ? i8[jj-1] : (here ? idx : i8[jj]);
                }
                bool top = (scr > v8[0]) || (scr == v8[0] && idx < i8[0]);
                if (top) { v8[0] = scr; i8[0] = idx; }
            }
        }
        int oi[9];
#pragma unroll
        for (int jj = 0; jj < 8; ++jj)
            oi[jj] = (i8[jj] == 0x7FFFFFFF) ? t : i8[jj];   // safety, never fires
        oi[8] = t;   // self (sim forced 1.1 -> always top-1)
        for (int a = 1; a < 9; ++a) {
            int kv = oi[a]; int jj = a - 1;
            while (jj >= 0 && oi[jj] > kv) { oi[jj+1] = oi[jj]; --jj; }
            oi[jj+1] = kv;
        }
        int* op = idxo + (bbase + t) * KK;
#pragma unroll
        for (int m = 0; m < 9; ++m) op[m] = oi[m];
    }
}

// ---------------------------------------------------------------------------
// Kernel 3: gather + conv1d(kernel=K, stride=K).
//   out[b][o][t] = sum_{k,c} W[o][c][k] * xfT[b][idx[b][t][k]][c]
// W in LDS as [k][c4][o] float4 -> contiguous b128 reads (conflict-free).
// Lane = o; wave owns 16 consecutive t -> results kept in regs, written as
// 4 float4 per lane (no LDS output buffer -> 2 blocks/CU).
// k-loop unroll capped at 2 -> bounded live set (R8 spill fix).
// Chain order per t identical to R7/R8 (4 chains by c4&3, pairwise combine).
// ---------------------------------------------------------------------------
__global__ __launch_bounds__(256) void gconv_kernel(
    const float* __restrict__ xfT, const int* __restrict__ idxi,
    const float* __restrict__ Wt, float* __restrict__ out)
{
    __shared__ float4 wl[KK * 8 * 64];   // 73.7 KB: [k][c4][o]

    int tid = threadIdx.x;
    int b   = blockIdx.y;
    int t0  = blockIdx.x * 64;
    size_t bbase = (size_t)b * TT;

    for (int f = tid; f < OC * 288; f += 256) {
        int o  = f / 288;
        int ck = f - o * 288;
        int c  = ck / KK;
        int k  = ck - c * KK;
        ((float*)wl)[(((k*8 + (c >> 2)) * 64 + o) << 2) + (c & 3)] = Wt[f];
    }
    __syncthreads();

    int w    = tid >> 6;
    int lane = tid & 63;        // = output channel o
    int tw0  = t0 + w * 16;

    float res[16];

    for (int i0 = 0; i0 < 16; i0 += 2) {
        float aa[2][4];
#pragma unroll
        for (int i = 0; i < 2; ++i)
#pragma unroll
            for (int q = 0; q < 4; ++q) aa[i][q] = 0.f;

        const int* ipa = idxi + (bbase + tw0 + i0) * KK;
        const int* ipb = ipa + KK;
#pragma unroll 2
        for (int k = 0; k < KK; ++k) {
            int sa = __builtin_amdgcn_readfirstlane(ipa[k]);
            int sb = __builtin_amdgcn_readfirstlane(ipb[k]);
            const float* ca = xfT + (bbase + sa) * CC;
            const float* cb = xfT + (bbase + sb) * CC;
#pragma unroll
            for (int c4 = 0; c4 < 8; ++c4) {
                float4 wv = wl[(k*8 + c4) * 64 + lane];
                int q = c4 & 3;
                float4 xa = *(const float4*)(ca + c4*4);
                aa[0][q] = fmaf(xa.x, wv.x, aa[0][q]); aa[0][q] = fmaf(xa.y, wv.y, aa[0][q]);
                aa[0][q] = fmaf(xa.z, wv.z, aa[0][q]); aa[0][q] = fmaf(xa.w, wv.w, aa[0][q]);
                float4 xb = *(const float4*)(cb + c4*4);
                aa[1][q] = fmaf(xb.x, wv.x, aa[1][q]); aa[1][q] = fmaf(xb.y, wv.y, aa[1][q]);
                aa[1][q] = fmaf(xb.z, wv.z, aa[1][q]); aa[1][q] = fmaf(xb.w, wv.w, aa[1][q]);
            }
            __builtin_amdgcn_sched_barrier(0);
        }
        res[i0]     = (aa[0][0] + aa[0][1]) + (aa[0][2] + aa[0][3]);
        res[i0 + 1] = (aa[1][0] + aa[1][1]) + (aa[1][2] + aa[1][3]);
    }

    // lane o owns out[b][o][tw0 .. tw0+15] -> 4 float4 stores (16B-aligned)
    float* op = out + ((size_t)b * OC + lane) * TT + tw0;
#pragma unroll
    for (int p = 0; p < 4; ++p)
        *(float4*)(op + p*4) = make_float4(res[p*4], res[p*4+1], res[p*4+2], res[p*4+3]);
}

// ---------------------------------------------------------------------------
extern "C" void kernel_launch(void* const* d_in, const int* in_sizes, int n_in,
                              void* d_out, int out_size, void* d_ws, size_t ws_size,
                              hipStream_t stream)
{
    const float* x  = (const float*)d_in[0];   // [8][32][56][56]
    const float* Wt = (const float*)d_in[1];   // [64][32][9]
    float* out = (float*)d_out;                // [8][64][56][56]

    // workspace: xnT (fp32, padded TTP) | xfT (fp32) | invn (fp64) | idx | thbuf
    float*  xnT  = (float*)d_ws;
    float*  xfT  = xnT + (size_t)BB * TTP * CC;
    double* invn = (double*)(xfT + (size_t)BB * TT * CC);
    int*    idw  = (int*)(invn + (size_t)BB * TT);
    float*  thb  = (float*)(idw + (size_t)BB * TT * KK);

    dim3 g1((TTP + 255) / 256, BB);
    norm_kernel<<<g1, 256, 0, stream>>>(x, xnT, xfT, invn);

    dim3 g2(TT / BR, BB);    // 98 x 8 = 784 blocks
    topk_a<<<g2, 256, 0, stream>>>(xnT, thb);
    topk_b<<<g2, 256, 0, stream>>>(xnT, xfT, invn, thb, idw);

    dim3 g3(TT / 64, BB);    // 49 x 8 = 392 blocks
    gconv_kernel<<<g3, 256, 0, stream>>>(xfT, idw, Wt, out);
}